// Round 19
// baseline (941.620 us; speedup 1.0000x reference)
//
#include <hip/hip_runtime.h>
#include <hip/hip_bf16.h>
#include <hip/hip_cooperative_groups.h>

namespace cg = cooperative_groups;

#define H 128
#define DOUT 32
#define NGRAPH 64
#define PCHUNK 64
#define SORT_TILE 4096
#define NBUCK_MAX 128

typedef __attribute__((ext_vector_type(8))) short bf16x8;
typedef __attribute__((ext_vector_type(4))) float f32x4;
typedef __attribute__((ext_vector_type(2))) float f32x2;
union U4B {
    uint4 u;
    bf16x8 b;
};

static __device__ __forceinline__ unsigned short f2bf(float v) {
    unsigned int u = __float_as_uint(v);
    unsigned int r = (u + 0x7FFFu + ((u >> 16) & 1u)) >> 16;
    return (unsigned short)r;
}
#define BFLO(w) __uint_as_float((w) << 16)
#define BFHI(w) __uint_as_float((w) & 0xFFFF0000u)

struct MegaParams {
    const float* x;
    const int* srcI;
    const int* dstI;
    const int* batch;
    const float* W1;
    const float* b1;
    const float* W2;
    const float* b2;
    const float* fW1;
    const float* fb1;
    const float* fW2;
    const float* fb2;
    float* out;
    int* row_ptr;
    int* col;
    float* dinv;
    int* gstart;
    int* bcnt;
    int* bstart;
    int* bfill;
    unsigned int* Wbf1;
    unsigned int* Wbf2;
    float* gsum;
    unsigned char* Af8;
    unsigned int* Bp;
    int N, E, bshift, nbuck, nst;
};

// ---- mm phase: MODE 0 = fp32 input, MODE 2 = fp8 input; output fp8 ----
template <int MODE>
static __device__ __forceinline__ void mm_phase(const void* Xv, const unsigned int* Wbf,
                                                const float* dinv, unsigned char* Out, int M,
                                                char* smraw, int bid, int t, int G) {
    unsigned int* wlds = (unsigned int*)smraw;
    const uint4* Wv = (const uint4*)Wbf;
#pragma unroll
    for (int it = 0; it < 8; ++it) ((uint4*)wlds)[t + it * 256] = Wv[t + it * 256];
    __syncthreads();
    int wv = t >> 6, l = t & 63;
    int l16 = l & 15, lk = l >> 4;
    int ntile = (M + 63) / 64;
    for (int tile = bid; tile < ntile; tile += G) {
        int rowbase = tile * 64 + wv * 16;
        f32x4 acc[8];
#pragma unroll
        for (int nt = 0; nt < 8; ++nt) acc[nt] = (f32x4){0.f, 0.f, 0.f, 0.f};
#pragma unroll
        for (int ks = 0; ks < 4; ++ks) {
            U4B afr;
            int row = rowbase + l16;
            if (MODE == 2) {
                uint2 v = make_uint2(0u, 0u);
                if (row < M) v = *((const uint2*)Xv + (size_t)row * 16 + 4 * ks + lk);
                f32x2 lo0 = __builtin_amdgcn_cvt_pk_f32_fp8((int)v.x, false);
                f32x2 hi0 = __builtin_amdgcn_cvt_pk_f32_fp8((int)v.x, true);
                f32x2 lo1 = __builtin_amdgcn_cvt_pk_f32_fp8((int)v.y, false);
                f32x2 hi1 = __builtin_amdgcn_cvt_pk_f32_fp8((int)v.y, true);
                afr.u.x = (unsigned int)f2bf(lo0[0]) | ((unsigned int)f2bf(lo0[1]) << 16);
                afr.u.y = (unsigned int)f2bf(hi0[0]) | ((unsigned int)f2bf(hi0[1]) << 16);
                afr.u.z = (unsigned int)f2bf(lo1[0]) | ((unsigned int)f2bf(lo1[1]) << 16);
                afr.u.w = (unsigned int)f2bf(hi1[0]) | ((unsigned int)f2bf(hi1[1]) << 16);
            } else {
                const float* X = (const float*)Xv;
                float4 v0 = make_float4(0.f, 0.f, 0.f, 0.f), v1 = v0;
                if (row < M) {
                    v0 = *reinterpret_cast<const float4*>(X + (size_t)row * H + 32 * ks + 8 * lk);
                    v1 = *reinterpret_cast<const float4*>(X + (size_t)row * H + 32 * ks + 8 * lk + 4);
                }
                afr.u.x = (unsigned int)f2bf(v0.x) | ((unsigned int)f2bf(v0.y) << 16);
                afr.u.y = (unsigned int)f2bf(v0.z) | ((unsigned int)f2bf(v0.w) << 16);
                afr.u.z = (unsigned int)f2bf(v1.x) | ((unsigned int)f2bf(v1.y) << 16);
                afr.u.w = (unsigned int)f2bf(v1.z) | ((unsigned int)f2bf(v1.w) << 16);
            }
#pragma unroll
            for (int nt = 0; nt < 8; ++nt) {
                int colB = nt * 16 + l16;
                int c = 4 * ks + lk;
                int p = c ^ (colB & 15);
                U4B bfr;
                bfr.u = *reinterpret_cast<const uint4*>(&wlds[colB * 64 + p * 4]);
                acc[nt] = __builtin_amdgcn_mfma_f32_16x16x32_bf16(afr.b, bfr.b, acc[nt], 0, 0, 0);
            }
        }
#pragma unroll
        for (int r = 0; r < 4; ++r) {
            int row = rowbase + lk * 4 + r;
            if (row < M) {
                float dsc = dinv[row];
                unsigned char* Orow = Out + (size_t)row * H;
#pragma unroll
                for (int nt = 0; nt < 8; ++nt) {
                    int pk8 = __builtin_amdgcn_cvt_pk_fp8_f32(acc[nt][r] * dsc, 0.f, 0, 0);
                    Orow[nt * 16 + l16] = (unsigned char)(pk8 & 0xFF);
                }
            }
        }
    }
}

// ---- agg phase: fp8 gathers, 16-deep, 2 rows/wave ----
template <int OUT_FP8>
static __device__ __forceinline__ void agg_phase(const unsigned int* Au,
                                                 const int* row_ptr, const int* col,
                                                 const float* dinv, const float* bias,
                                                 unsigned int* OutP, int N, int bid, int t,
                                                 int G) {
    int wave = t >> 6, lane = t & 63;
    int half = lane >> 5, fl = lane & 31;
    int ngrp = (N + 7) / 8;
    for (int grp = bid; grp < ngrp; grp += G) {
        int i = grp * 8 + wave * 2 + half;
        if (i >= N) continue;
        int s = row_ptr[i], e = row_ptr[i + 1];
        unsigned int ws = Au[(size_t)i * 32 + fl];
        f32x2 slo = __builtin_amdgcn_cvt_pk_f32_fp8((int)ws, false);
        f32x2 shi = __builtin_amdgcn_cvt_pk_f32_fp8((int)ws, true);
        float a0 = slo[0], a1 = slo[1], a2 = shi[0], a3 = shi[1];
        int j = s;
        for (; j + 16 <= e; j += 16) {
            unsigned int w[16];
#pragma unroll
            for (int q = 0; q < 16; ++q) w[q] = Au[(size_t)col[j + q] * 32 + fl];
#pragma unroll
            for (int q = 0; q < 16; ++q) {
                f32x2 lo = __builtin_amdgcn_cvt_pk_f32_fp8((int)w[q], false);
                f32x2 hi = __builtin_amdgcn_cvt_pk_f32_fp8((int)w[q], true);
                a0 += lo[0];
                a1 += lo[1];
                a2 += hi[0];
                a3 += hi[1];
            }
        }
        for (; j + 4 <= e; j += 4) {
            unsigned int w[4];
#pragma unroll
            for (int q = 0; q < 4; ++q) w[q] = Au[(size_t)col[j + q] * 32 + fl];
#pragma unroll
            for (int q = 0; q < 4; ++q) {
                f32x2 lo = __builtin_amdgcn_cvt_pk_f32_fp8((int)w[q], false);
                f32x2 hi = __builtin_amdgcn_cvt_pk_f32_fp8((int)w[q], true);
                a0 += lo[0];
                a1 += lo[1];
                a2 += hi[0];
                a3 += hi[1];
            }
        }
        for (; j < e; ++j) {
            unsigned int w = Au[(size_t)col[j] * 32 + fl];
            f32x2 lo = __builtin_amdgcn_cvt_pk_f32_fp8((int)w, false);
            f32x2 hi = __builtin_amdgcn_cvt_pk_f32_fp8((int)w, true);
            a0 += lo[0];
            a1 += lo[1];
            a2 += hi[0];
            a3 += hi[1];
        }
        float d = dinv[i];
        float4 bs = *reinterpret_cast<const float4*>(bias + 4 * fl);
        float o0 = fmaxf(fmaf(d, a0, bs.x), 0.f);
        float o1 = fmaxf(fmaf(d, a1, bs.y), 0.f);
        float o2 = fmaxf(fmaf(d, a2, bs.z), 0.f);
        float o3 = fmaxf(fmaf(d, a3, bs.w), 0.f);
        if (OUT_FP8) {
            int pk = __builtin_amdgcn_cvt_pk_fp8_f32(o0, o1, 0, false);
            pk = __builtin_amdgcn_cvt_pk_fp8_f32(o2, o3, pk, true);
            OutP[(size_t)i * 32 + fl] = (unsigned int)pk;
        } else {
            uint2 o;
            o.x = (unsigned int)f2bf(o0) | ((unsigned int)f2bf(o1) << 16);
            o.y = (unsigned int)f2bf(o2) | ((unsigned int)f2bf(o3) << 16);
            ((uint2*)OutP)[(size_t)i * 32 + fl] = o;
        }
    }
}

__global__ __launch_bounds__(256, 4) void mega_kernel(MegaParams P) {
    cg::grid_group grid = cg::this_grid();
    __shared__ char smraw[32768];
    int bid = blockIdx.x, t = threadIdx.x, G = gridDim.x;
    int wave = t >> 6, lane = t & 63;
    unsigned int mask = (1u << P.bshift) - 1u;

    // ---- P0: init (gsum/bcnt zero; W prep; batch bounds) ----
    if (bid == 0) {
        for (int j = t; j < NGRAPH * H; j += 256) P.gsum[j] = 0.f;
        if (t < NBUCK_MAX) P.bcnt[t] = 0;
    } else if (bid <= 64) {
        int pb = bid - 1;
        const float* W = (pb < 32) ? P.W1 : P.W2;
        unsigned int* Wb = (pb < 32) ? P.Wbf1 : P.Wbf2;
        int q = (pb & 31) * 256 + t;
        int colq = q >> 6, j = q & 63;
        int p = j >> 2, wI = j & 3;
        int cq = p ^ (colq & 15);
        int k0 = 8 * cq + 2 * wI;
        Wb[q] = (unsigned int)f2bf(W[k0 * H + colq]) |
                ((unsigned int)f2bf(W[(k0 + 1) * H + colq]) << 16);
    } else {
        for (int c = bid - 65; c * 256 < P.N; c += G - 65) {
            int i = c * 256 + t;
            if (i < P.N) {
                int bb = P.batch[i];
                int bp = (i == 0) ? -1 : P.batch[i - 1];
                for (int g = bp + 1; g <= bb; ++g) P.gstart[g] = i;
                if (i == P.N - 1)
                    for (int g = bb + 1; g <= NGRAPH; ++g) P.gstart[g] = P.N;
            }
        }
    }
    grid.sync();

    // ---- P1: bucket histogram ----
    {
        int* lh = (int*)smraw;
        for (int tile = bid; tile < P.nst; tile += G) {
            if (t < NBUCK_MAX) lh[t] = 0;
            __syncthreads();
            int base = tile * SORT_TILE;
            int cnt = P.E - base;
            if (cnt > SORT_TILE) cnt = SORT_TILE;
            for (int j = t; j < cnt; j += 256) atomicAdd(&lh[P.dstI[base + j] >> P.bshift], 1);
            __syncthreads();
            if (t < NBUCK_MAX && lh[t]) atomicAdd(&P.bcnt[t], lh[t]);
            __syncthreads();
        }
    }
    grid.sync();

    // ---- P2: bucket scan ----
    if (bid == 0 && t == 0) {
        int run = 0;
        for (int k = 0; k < P.nbuck; ++k) {
            P.bstart[k] = run;
            P.bfill[k] = run;
            run += P.bcnt[k];
        }
        P.bstart[P.nbuck] = run;
    }
    grid.sync();

    // ---- P3: scatter (direct write) ----
    unsigned int* es = (unsigned int*)P.Af8;
    {
        int* lh = (int*)smraw;
        int* lfill = lh + NBUCK_MAX;
        int* gbase = lfill + NBUCK_MAX;
        for (int tile = bid; tile < P.nst; tile += G) {
            if (t < NBUCK_MAX) {
                lh[t] = 0;
                lfill[t] = 0;
            }
            __syncthreads();
            int base = tile * SORT_TILE;
            int cnt = P.E - base;
            if (cnt > SORT_TILE) cnt = SORT_TILE;
            for (int j = t; j < cnt; j += 256) atomicAdd(&lh[P.dstI[base + j] >> P.bshift], 1);
            __syncthreads();
            if (t < NBUCK_MAX && lh[t] > 0) gbase[t] = atomicAdd(&P.bfill[t], lh[t]);
            __syncthreads();
            for (int j = t; j < cnt; j += 256) {
                int d = P.dstI[base + j];
                int b = d >> P.bshift;
                int r = atomicAdd(&lfill[b], 1);
                es[gbase[b] + r] =
                    ((unsigned int)P.srcI[base + j] << P.bshift) | ((unsigned int)d & mask);
            }
            __syncthreads();
        }
    }
    grid.sync();

    // ---- P4: per-bucket counting sort (256 threads, 4 nodes/thread) ----
    {
        int* cnt = (int*)smraw;
        int* sc = cnt + 1024;
        int* wsum = sc + 1024;
        for (int b = bid; b < P.nbuck; b += G) {
            int nodebase = b << P.bshift;
            int nodes_here = P.N - nodebase;
            if (nodes_here > 1024) nodes_here = 1024;
            int s = P.bstart[b], e = P.bstart[b + 1];
            cnt[t] = 0;
            cnt[t + 256] = 0;
            cnt[t + 512] = 0;
            cnt[t + 768] = 0;
            __syncthreads();
            for (int j = s + t; j < e; j += 256) atomicAdd(&cnt[es[j] & mask], 1);
            __syncthreads();
            int c0 = cnt[4 * t], c1 = cnt[4 * t + 1], c2 = cnt[4 * t + 2], c3 = cnt[4 * t + 3];
            int tc = c0 + c1 + c2 + c3;
            int v = tc;
#pragma unroll
            for (int off = 1; off < 64; off <<= 1) {
                int x = __shfl_up(v, off);
                if (lane >= off) v += x;
            }
            if (lane == 63) wsum[wave] = v;
            __syncthreads();
            int woff = 0;
            for (int k = 0; k < wave; ++k) woff += wsum[k];
            int e0 = woff + v - tc;
            int e1 = e0 + c0, e2 = e1 + c1, e3 = e2 + c2;
            sc[4 * t] = e0;
            sc[4 * t + 1] = e1;
            sc[4 * t + 2] = e2;
            sc[4 * t + 3] = e3;
            int exl[4] = {e0, e1, e2, e3};
            int cl[4] = {c0, c1, c2, c3};
#pragma unroll
            for (int k = 0; k < 4; ++k) {
                int idx = 4 * t + k;
                if (idx < nodes_here) {
                    P.row_ptr[nodebase + idx] = s + exl[k];
                    P.dinv[nodebase + idx] = rsqrtf(1.0f + (float)cl[k]);
                }
            }
            if (b == P.nbuck - 1 && t == 0) P.row_ptr[P.N] = P.E;
            __syncthreads();
            for (int j = s + t; j < e; j += 256) {
                unsigned int p = es[j];
                int local = p & mask;
                int pos = s + atomicAdd(&sc[local], 1);
                P.col[pos] = (int)(p >> P.bshift);
            }
            __syncthreads();
        }
    }
    grid.sync();

    // ---- P5: mm1 (fp32 -> fp8) ----
    mm_phase<0>(P.x, P.Wbf1, P.dinv, P.Af8, P.N, smraw, bid, t, G);
    grid.sync();

    // ---- P6: agg1 (fp8 out -> Bp) ----
    agg_phase<1>((const unsigned int*)P.Af8, P.row_ptr, P.col, P.dinv, P.b1, P.Bp, P.N, bid, t,
                 G);
    grid.sync();

    // ---- P7: mm2 (fp8 -> fp8) ----
    mm_phase<2>(P.Bp, P.Wbf2, P.dinv, P.Af8, P.N, smraw, bid, t, G);
    grid.sync();

    // ---- P8: agg2 (bf16 out -> Bp) ----
    agg_phase<0>((const unsigned int*)P.Af8, P.row_ptr, P.col, P.dinv, P.b2, P.Bp, P.N, bid, t,
                 G);
    grid.sync();

    // ---- P9: pool (per-wave chunks, barrier-free) ----
    {
        int* sbp = (int*)smraw + wave * PCHUNK;
        int nchunk = (P.N + PCHUNK - 1) / PCHUNK;
        const unsigned int* Bu = P.Bp;
        for (int c = bid * 4 + wave; c < nchunk; c += G * 4) {
            int base = c * PCHUNK;
            int n_here = P.N - base;
            if (n_here > PCHUNK) n_here = PCHUNK;
            for (int j = lane; j < n_here; j += 64) sbp[j] = P.batch[base + j];
            __builtin_amdgcn_s_waitcnt(0);  // ensure LDS writes visible within wave
            float acc0 = 0.f, acc1 = 0.f;
            int cur = sbp[0];
            int j = 0;
            while (j < n_here) {
                if (j + 4 <= n_here && sbp[j] == cur && sbp[j + 1] == cur && sbp[j + 2] == cur &&
                    sbp[j + 3] == cur) {
                    unsigned int w0 = Bu[(size_t)(base + j) * 64 + lane];
                    unsigned int w1 = Bu[(size_t)(base + j + 1) * 64 + lane];
                    unsigned int w2 = Bu[(size_t)(base + j + 2) * 64 + lane];
                    unsigned int w3 = Bu[(size_t)(base + j + 3) * 64 + lane];
                    acc0 += BFLO(w0) + BFLO(w1);
                    acc1 += BFHI(w0) + BFHI(w1);
                    acc0 += BFLO(w2) + BFLO(w3);
                    acc1 += BFHI(w2) + BFHI(w3);
                    j += 4;
                } else {
                    int g = sbp[j];
                    if (g != cur) {
                        atomicAdd(&P.gsum[cur * H + 2 * lane], acc0);
                        atomicAdd(&P.gsum[cur * H + 2 * lane + 1], acc1);
                        acc0 = 0.f;
                        acc1 = 0.f;
                        cur = g;
                    }
                    unsigned int w = Bu[(size_t)(base + j) * 64 + lane];
                    acc0 += BFLO(w);
                    acc1 += BFHI(w);
                    ++j;
                }
            }
            atomicAdd(&P.gsum[cur * H + 2 * lane], acc0);
            atomicAdd(&P.gsum[cur * H + 2 * lane + 1], acc1);
        }
    }
    grid.sync();

    // ---- P10: head (blocks 0..63) ----
    if (bid < NGRAPH) {
        float* gv = (float*)smraw;
        float* hid = gv + H;
        float* lg = hid + H;
        int gr = bid, f = t;
        int cntg = P.gstart[gr + 1] - P.gstart[gr];
        if (f < H) gv[f] = P.gsum[gr * H + f] / fmaxf((float)cntg, 1.f);
        __syncthreads();
        if (f < H) {
            float acc = P.fb1[f];
            for (int k = 0; k < H; ++k) acc = fmaf(gv[k], P.fW1[k * H + f], acc);
            hid[f] = fmaxf(acc, 0.f);
        }
        __syncthreads();
        if (f < DOUT) {
            float a = P.fb2[f];
            for (int k = 0; k < H; ++k) a = fmaf(hid[k], P.fW2[k * DOUT + f], a);
            lg[f] = a;
        }
        __syncthreads();
        if (f < DOUT) {
            float mx = -1e30f;
            for (int j = 0; j < DOUT; ++j) mx = fmaxf(mx, lg[j]);
            float ssum = 0.f;
            for (int j = 0; j < DOUT; ++j) ssum += expf(lg[j] - mx);
            P.out[gr * DOUT + f] = expf(lg[f] - mx) / ssum;
        }
    }
}

// ---------------- launch ----------------

extern "C" void kernel_launch(void* const* d_in, const int* in_sizes, int n_in,
                              void* d_out, int out_size, void* d_ws, size_t ws_size,
                              hipStream_t stream) {
    int N = in_sizes[0] / H;
    int E = in_sizes[1] / 2;

    char* ws = (char*)d_ws;
    size_t off = 0;
    auto alloc = [&](size_t bytes) {
        void* p = ws + off;
        off = (off + bytes + 255) & ~(size_t)255;
        return p;
    };
    int* row_ptr = (int*)alloc((size_t)(N + 1) * 4);
    int* col = (int*)alloc((size_t)E * 4);
    float* dinv = (float*)alloc((size_t)N * 4);
    int* gstart = (int*)alloc(512);
    int* bcnt = (int*)alloc(NBUCK_MAX * 4);
    int* bstart = (int*)alloc((NBUCK_MAX + 1) * 4);
    int* bfill = (int*)alloc(NBUCK_MAX * 4);
    unsigned int* Wbf1 = (unsigned int*)alloc(128 * 64 * 4);
    unsigned int* Wbf2 = (unsigned int*)alloc(128 * 64 * 4);
    float* gsum = (float*)alloc((size_t)NGRAPH * H * 4);
    unsigned char* Af8 = (unsigned char*)alloc((size_t)N * H * 4);
    unsigned int* Bp = (unsigned int*)alloc((size_t)N * H * 4);
    (void)ws_size;

    int bshift = 0;
    while (((N - 1) >> bshift) >= NBUCK_MAX) ++bshift;
    int nbuck = ((N - 1) >> bshift) + 1;
    int nst = (E + SORT_TILE - 1) / SORT_TILE;

    MegaParams mp;
    mp.x = (const float*)d_in[0];
    mp.srcI = (const int*)d_in[1];
    mp.dstI = (const int*)d_in[1] + E;
    mp.batch = (const int*)d_in[2];
    mp.W1 = (const float*)d_in[3];
    mp.b1 = (const float*)d_in[4];
    mp.W2 = (const float*)d_in[5];
    mp.b2 = (const float*)d_in[6];
    mp.fW1 = (const float*)d_in[7];
    mp.fb1 = (const float*)d_in[8];
    mp.fW2 = (const float*)d_in[9];
    mp.fb2 = (const float*)d_in[10];
    mp.out = (float*)d_out;
    mp.row_ptr = row_ptr;
    mp.col = col;
    mp.dinv = dinv;
    mp.gstart = gstart;
    mp.bcnt = bcnt;
    mp.bstart = bstart;
    mp.bfill = bfill;
    mp.Wbf1 = Wbf1;
    mp.Wbf2 = Wbf2;
    mp.gsum = gsum;
    mp.Af8 = Af8;
    mp.Bp = Bp;
    mp.N = N;
    mp.E = E;
    mp.bshift = bshift;
    mp.nbuck = nbuck;
    mp.nst = nst;

    int maxb = 0;
    hipOccupancyMaxActiveBlocksPerMultiprocessor(&maxb, (const void*)mega_kernel, 256, 0);
    if (maxb < 1) maxb = 1;
    int dev = 0;
    hipGetDevice(&dev);
    hipDeviceProp_t prop;
    hipGetDeviceProperties(&prop, dev);
    int ncu = prop.multiProcessorCount;
    if (ncu < 1) ncu = 256;
    long long cap = (long long)maxb * ncu;
    int G = (cap > 2048) ? 2048 : (int)cap;
    if (G < 66) G = 66;  // need W-prep role blocks; MI355X capacity >= 256 regardless

    void* args[] = {&mp};
    hipLaunchCooperativeKernel((const void*)mega_kernel, dim3(G), dim3(256), args, 0, stream);
}

// Round 20
// 941.055 us; speedup vs baseline: 1.0006x; 1.0006x over previous
//
#include <hip/hip_runtime.h>
#include <hip/hip_bf16.h>
#include <hip/hip_cooperative_groups.h>

namespace cg = cooperative_groups;

#define H 128
#define DOUT 32
#define NGRAPH 64
#define PCHUNK 64
#define SORT_TILE 4096
#define NBUCK_MAX 128

typedef __attribute__((ext_vector_type(8))) short bf16x8;
typedef __attribute__((ext_vector_type(4))) float f32x4;
typedef __attribute__((ext_vector_type(2))) float f32x2;
union U4B {
    uint4 u;
    bf16x8 b;
};

static __device__ __forceinline__ unsigned short f2bf(float v) {
    unsigned int u = __float_as_uint(v);
    unsigned int r = (u + 0x7FFFu + ((u >> 16) & 1u)) >> 16;
    return (unsigned short)r;
}
#define BFLO(w) __uint_as_float((w) << 16)
#define BFHI(w) __uint_as_float((w) & 0xFFFF0000u)

struct MegaParams {
    const float* x;
    const int* srcI;
    const int* dstI;
    const int* batch;
    const float* W1;
    const float* b1;
    const float* W2;
    const float* b2;
    const float* fW1;
    const float* fb1;
    const float* fW2;
    const float* fb2;
    float* out;
    int* row_ptr;
    int* col;
    float* dinv;
    int* gstart;
    int* bcnt;
    int* bstart;
    int* bfill;
    unsigned int* Wbf1;
    unsigned int* Wbf2;
    float* gsum;
    unsigned char* Af8;
    unsigned int* Bp;
    int N, E, bshift, nbuck, nst;
};

// ---- mm phase: MODE 0 = fp32 input, MODE 2 = fp8 input; output fp8 ----
template <int MODE>
static __device__ __forceinline__ void mm_phase(const void* Xv, const unsigned int* Wbf,
                                                const float* dinv, unsigned char* Out, int M,
                                                char* smraw, int bid, int t, int G) {
    unsigned int* wlds = (unsigned int*)smraw;
    const uint4* Wv = (const uint4*)Wbf;
#pragma unroll
    for (int it = 0; it < 8; ++it) ((uint4*)wlds)[t + it * 256] = Wv[t + it * 256];
    __syncthreads();
    int wv = t >> 6, l = t & 63;
    int l16 = l & 15, lk = l >> 4;
    int ntile = (M + 63) / 64;
    for (int tile = bid; tile < ntile; tile += G) {
        int rowbase = tile * 64 + wv * 16;
        f32x4 acc[8];
#pragma unroll
        for (int nt = 0; nt < 8; ++nt) acc[nt] = (f32x4){0.f, 0.f, 0.f, 0.f};
#pragma unroll
        for (int ks = 0; ks < 4; ++ks) {
            U4B afr;
            int row = rowbase + l16;
            if (MODE == 2) {
                uint2 v = make_uint2(0u, 0u);
                if (row < M) v = *((const uint2*)Xv + (size_t)row * 16 + 4 * ks + lk);
                f32x2 lo0 = __builtin_amdgcn_cvt_pk_f32_fp8((int)v.x, false);
                f32x2 hi0 = __builtin_amdgcn_cvt_pk_f32_fp8((int)v.x, true);
                f32x2 lo1 = __builtin_amdgcn_cvt_pk_f32_fp8((int)v.y, false);
                f32x2 hi1 = __builtin_amdgcn_cvt_pk_f32_fp8((int)v.y, true);
                afr.u.x = (unsigned int)f2bf(lo0[0]) | ((unsigned int)f2bf(lo0[1]) << 16);
                afr.u.y = (unsigned int)f2bf(hi0[0]) | ((unsigned int)f2bf(hi0[1]) << 16);
                afr.u.z = (unsigned int)f2bf(lo1[0]) | ((unsigned int)f2bf(lo1[1]) << 16);
                afr.u.w = (unsigned int)f2bf(hi1[0]) | ((unsigned int)f2bf(hi1[1]) << 16);
            } else {
                const float* X = (const float*)Xv;
                float4 v0 = make_float4(0.f, 0.f, 0.f, 0.f), v1 = v0;
                if (row < M) {
                    v0 = *reinterpret_cast<const float4*>(X + (size_t)row * H + 32 * ks + 8 * lk);
                    v1 = *reinterpret_cast<const float4*>(X + (size_t)row * H + 32 * ks + 8 * lk + 4);
                }
                afr.u.x = (unsigned int)f2bf(v0.x) | ((unsigned int)f2bf(v0.y) << 16);
                afr.u.y = (unsigned int)f2bf(v0.z) | ((unsigned int)f2bf(v0.w) << 16);
                afr.u.z = (unsigned int)f2bf(v1.x) | ((unsigned int)f2bf(v1.y) << 16);
                afr.u.w = (unsigned int)f2bf(v1.z) | ((unsigned int)f2bf(v1.w) << 16);
            }
#pragma unroll
            for (int nt = 0; nt < 8; ++nt) {
                int colB = nt * 16 + l16;
                int c = 4 * ks + lk;
                int p = c ^ (colB & 15);
                U4B bfr;
                bfr.u = *reinterpret_cast<const uint4*>(&wlds[colB * 64 + p * 4]);
                acc[nt] = __builtin_amdgcn_mfma_f32_16x16x32_bf16(afr.b, bfr.b, acc[nt], 0, 0, 0);
            }
        }
#pragma unroll
        for (int r = 0; r < 4; ++r) {
            int row = rowbase + lk * 4 + r;
            if (row < M) {
                float dsc = dinv[row];
                unsigned char* Orow = Out + (size_t)row * H;
#pragma unroll
                for (int nt = 0; nt < 8; ++nt) {
                    int pk8 = __builtin_amdgcn_cvt_pk_fp8_f32(acc[nt][r] * dsc, 0.f, 0, 0);
                    Orow[nt * 16 + l16] = (unsigned char)(pk8 & 0xFF);
                }
            }
        }
    }
}

// ---- agg phase: fp8 gathers, 16-deep, 2 rows/wave ----
template <int OUT_FP8>
static __device__ __forceinline__ void agg_phase(const unsigned int* Au,
                                                 const int* row_ptr, const int* col,
                                                 const float* dinv, const float* bias,
                                                 unsigned int* OutP, int N, int bid, int t,
                                                 int G) {
    int wave = t >> 6, lane = t & 63;
    int half = lane >> 5, fl = lane & 31;
    int ngrp = (N + 7) / 8;
    for (int grp = bid; grp < ngrp; grp += G) {
        int i = grp * 8 + wave * 2 + half;
        if (i >= N) continue;
        int s = row_ptr[i], e = row_ptr[i + 1];
        unsigned int ws = Au[(size_t)i * 32 + fl];
        f32x2 slo = __builtin_amdgcn_cvt_pk_f32_fp8((int)ws, false);
        f32x2 shi = __builtin_amdgcn_cvt_pk_f32_fp8((int)ws, true);
        float a0 = slo[0], a1 = slo[1], a2 = shi[0], a3 = shi[1];
        int j = s;
        for (; j + 16 <= e; j += 16) {
            unsigned int w[16];
#pragma unroll
            for (int q = 0; q < 16; ++q) w[q] = Au[(size_t)col[j + q] * 32 + fl];
#pragma unroll
            for (int q = 0; q < 16; ++q) {
                f32x2 lo = __builtin_amdgcn_cvt_pk_f32_fp8((int)w[q], false);
                f32x2 hi = __builtin_amdgcn_cvt_pk_f32_fp8((int)w[q], true);
                a0 += lo[0];
                a1 += lo[1];
                a2 += hi[0];
                a3 += hi[1];
            }
        }
        for (; j + 4 <= e; j += 4) {
            unsigned int w[4];
#pragma unroll
            for (int q = 0; q < 4; ++q) w[q] = Au[(size_t)col[j + q] * 32 + fl];
#pragma unroll
            for (int q = 0; q < 4; ++q) {
                f32x2 lo = __builtin_amdgcn_cvt_pk_f32_fp8((int)w[q], false);
                f32x2 hi = __builtin_amdgcn_cvt_pk_f32_fp8((int)w[q], true);
                a0 += lo[0];
                a1 += lo[1];
                a2 += hi[0];
                a3 += hi[1];
            }
        }
        for (; j < e; ++j) {
            unsigned int w = Au[(size_t)col[j] * 32 + fl];
            f32x2 lo = __builtin_amdgcn_cvt_pk_f32_fp8((int)w, false);
            f32x2 hi = __builtin_amdgcn_cvt_pk_f32_fp8((int)w, true);
            a0 += lo[0];
            a1 += lo[1];
            a2 += hi[0];
            a3 += hi[1];
        }
        float d = dinv[i];
        float4 bs = *reinterpret_cast<const float4*>(bias + 4 * fl);
        float o0 = fmaxf(fmaf(d, a0, bs.x), 0.f);
        float o1 = fmaxf(fmaf(d, a1, bs.y), 0.f);
        float o2 = fmaxf(fmaf(d, a2, bs.z), 0.f);
        float o3 = fmaxf(fmaf(d, a3, bs.w), 0.f);
        if (OUT_FP8) {
            int pk = __builtin_amdgcn_cvt_pk_fp8_f32(o0, o1, 0, false);
            pk = __builtin_amdgcn_cvt_pk_fp8_f32(o2, o3, pk, true);
            OutP[(size_t)i * 32 + fl] = (unsigned int)pk;
        } else {
            uint2 o;
            o.x = (unsigned int)f2bf(o0) | ((unsigned int)f2bf(o1) << 16);
            o.y = (unsigned int)f2bf(o2) | ((unsigned int)f2bf(o3) << 16);
            ((uint2*)OutP)[(size_t)i * 32 + fl] = o;
        }
    }
}

__global__ __launch_bounds__(256, 4) void mega_kernel(MegaParams P) {
    cg::grid_group grid = cg::this_grid();
    __shared__ char smraw[32768];
    int bid = blockIdx.x, t = threadIdx.x, G = gridDim.x;
    int wave = t >> 6, lane = t & 63;
    unsigned int mask = (1u << P.bshift) - 1u;

    // ---- P0: init (gsum/bcnt zero; W prep; batch bounds) ----
    if (bid == 0) {
        for (int j = t; j < NGRAPH * H; j += 256) P.gsum[j] = 0.f;
        if (t < NBUCK_MAX) P.bcnt[t] = 0;
    } else if (bid <= 64) {
        int pb = bid - 1;
        const float* W = (pb < 32) ? P.W1 : P.W2;
        unsigned int* Wb = (pb < 32) ? P.Wbf1 : P.Wbf2;
        int q = (pb & 31) * 256 + t;
        int colq = q >> 6, j = q & 63;
        int p = j >> 2, wI = j & 3;
        int cq = p ^ (colq & 15);
        int k0 = 8 * cq + 2 * wI;
        Wb[q] = (unsigned int)f2bf(W[k0 * H + colq]) |
                ((unsigned int)f2bf(W[(k0 + 1) * H + colq]) << 16);
    } else {
        for (int c = bid - 65; c * 256 < P.N; c += G - 65) {
            int i = c * 256 + t;
            if (i < P.N) {
                int bb = P.batch[i];
                int bp = (i == 0) ? -1 : P.batch[i - 1];
                for (int g = bp + 1; g <= bb; ++g) P.gstart[g] = i;
                if (i == P.N - 1)
                    for (int g = bb + 1; g <= NGRAPH; ++g) P.gstart[g] = P.N;
            }
        }
    }
    grid.sync();

    // ---- P1: bucket histogram ----
    {
        int* lh = (int*)smraw;
        for (int tile = bid; tile < P.nst; tile += G) {
            if (t < NBUCK_MAX) lh[t] = 0;
            __syncthreads();
            int base = tile * SORT_TILE;
            int cnt = P.E - base;
            if (cnt > SORT_TILE) cnt = SORT_TILE;
            for (int j = t; j < cnt; j += 256) atomicAdd(&lh[P.dstI[base + j] >> P.bshift], 1);
            __syncthreads();
            if (t < NBUCK_MAX && lh[t]) atomicAdd(&P.bcnt[t], lh[t]);
            __syncthreads();
        }
    }
    grid.sync();

    // ---- P2: bucket scan ----
    if (bid == 0 && t == 0) {
        int run = 0;
        for (int k = 0; k < P.nbuck; ++k) {
            P.bstart[k] = run;
            P.bfill[k] = run;
            run += P.bcnt[k];
        }
        P.bstart[P.nbuck] = run;
    }
    grid.sync();

    // ---- P3: scatter (direct write) ----
    unsigned int* es = (unsigned int*)P.Af8;
    {
        int* lh = (int*)smraw;
        int* lfill = lh + NBUCK_MAX;
        int* gbase = lfill + NBUCK_MAX;
        for (int tile = bid; tile < P.nst; tile += G) {
            if (t < NBUCK_MAX) {
                lh[t] = 0;
                lfill[t] = 0;
            }
            __syncthreads();
            int base = tile * SORT_TILE;
            int cnt = P.E - base;
            if (cnt > SORT_TILE) cnt = SORT_TILE;
            for (int j = t; j < cnt; j += 256) atomicAdd(&lh[P.dstI[base + j] >> P.bshift], 1);
            __syncthreads();
            if (t < NBUCK_MAX && lh[t] > 0) gbase[t] = atomicAdd(&P.bfill[t], lh[t]);
            __syncthreads();
            for (int j = t; j < cnt; j += 256) {
                int d = P.dstI[base + j];
                int b = d >> P.bshift;
                int r = atomicAdd(&lfill[b], 1);
                es[gbase[b] + r] =
                    ((unsigned int)P.srcI[base + j] << P.bshift) | ((unsigned int)d & mask);
            }
            __syncthreads();
        }
    }
    grid.sync();

    // ---- P4: per-bucket counting sort (256 threads, 4 nodes/thread) ----
    {
        int* cnt = (int*)smraw;
        int* sc = cnt + 1024;
        int* wsum = sc + 1024;
        for (int b = bid; b < P.nbuck; b += G) {
            int nodebase = b << P.bshift;
            int nodes_here = P.N - nodebase;
            if (nodes_here > 1024) nodes_here = 1024;
            int s = P.bstart[b], e = P.bstart[b + 1];
            cnt[t] = 0;
            cnt[t + 256] = 0;
            cnt[t + 512] = 0;
            cnt[t + 768] = 0;
            __syncthreads();
            for (int j = s + t; j < e; j += 256) atomicAdd(&cnt[es[j] & mask], 1);
            __syncthreads();
            int c0 = cnt[4 * t], c1 = cnt[4 * t + 1], c2 = cnt[4 * t + 2], c3 = cnt[4 * t + 3];
            int tc = c0 + c1 + c2 + c3;
            int v = tc;
#pragma unroll
            for (int off = 1; off < 64; off <<= 1) {
                int x = __shfl_up(v, off);
                if (lane >= off) v += x;
            }
            if (lane == 63) wsum[wave] = v;
            __syncthreads();
            int woff = 0;
            for (int k = 0; k < wave; ++k) woff += wsum[k];
            int e0 = woff + v - tc;
            int e1 = e0 + c0, e2 = e1 + c1, e3 = e2 + c2;
            sc[4 * t] = e0;
            sc[4 * t + 1] = e1;
            sc[4 * t + 2] = e2;
            sc[4 * t + 3] = e3;
            int exl[4] = {e0, e1, e2, e3};
            int cl[4] = {c0, c1, c2, c3};
#pragma unroll
            for (int k = 0; k < 4; ++k) {
                int idx = 4 * t + k;
                if (idx < nodes_here) {
                    P.row_ptr[nodebase + idx] = s + exl[k];
                    P.dinv[nodebase + idx] = rsqrtf(1.0f + (float)cl[k]);
                }
            }
            if (b == P.nbuck - 1 && t == 0) P.row_ptr[P.N] = P.E;
            __syncthreads();
            for (int j = s + t; j < e; j += 256) {
                unsigned int p = es[j];
                int local = p & mask;
                int pos = s + atomicAdd(&sc[local], 1);
                P.col[pos] = (int)(p >> P.bshift);
            }
            __syncthreads();
        }
    }
    grid.sync();

    // ---- P5: mm1 (fp32 -> fp8) ----
    mm_phase<0>(P.x, P.Wbf1, P.dinv, P.Af8, P.N, smraw, bid, t, G);
    grid.sync();

    // ---- P6: agg1 (fp8 out -> Bp) ----
    agg_phase<1>((const unsigned int*)P.Af8, P.row_ptr, P.col, P.dinv, P.b1, P.Bp, P.N, bid, t,
                 G);
    grid.sync();

    // ---- P7: mm2 (fp8 -> fp8) ----
    mm_phase<2>(P.Bp, P.Wbf2, P.dinv, P.Af8, P.N, smraw, bid, t, G);
    grid.sync();

    // ---- P8: agg2 (bf16 out -> Bp) ----
    agg_phase<0>((const unsigned int*)P.Af8, P.row_ptr, P.col, P.dinv, P.b2, P.Bp, P.N, bid, t,
                 G);
    grid.sync();

    // ---- P9: pool (per-wave chunks, barrier-free) ----
    {
        int* sbp = (int*)smraw + wave * PCHUNK;
        int nchunk = (P.N + PCHUNK - 1) / PCHUNK;
        const unsigned int* Bu = P.Bp;
        for (int c = bid * 4 + wave; c < nchunk; c += G * 4) {
            int base = c * PCHUNK;
            int n_here = P.N - base;
            if (n_here > PCHUNK) n_here = PCHUNK;
            for (int j = lane; j < n_here; j += 64) sbp[j] = P.batch[base + j];
            __builtin_amdgcn_s_waitcnt(0);  // ensure LDS writes visible within wave
            float acc0 = 0.f, acc1 = 0.f;
            int cur = sbp[0];
            int j = 0;
            while (j < n_here) {
                if (j + 4 <= n_here && sbp[j] == cur && sbp[j + 1] == cur && sbp[j + 2] == cur &&
                    sbp[j + 3] == cur) {
                    unsigned int w0 = Bu[(size_t)(base + j) * 64 + lane];
                    unsigned int w1 = Bu[(size_t)(base + j + 1) * 64 + lane];
                    unsigned int w2 = Bu[(size_t)(base + j + 2) * 64 + lane];
                    unsigned int w3 = Bu[(size_t)(base + j + 3) * 64 + lane];
                    acc0 += BFLO(w0) + BFLO(w1);
                    acc1 += BFHI(w0) + BFHI(w1);
                    acc0 += BFLO(w2) + BFLO(w3);
                    acc1 += BFHI(w2) + BFHI(w3);
                    j += 4;
                } else {
                    int g = sbp[j];
                    if (g != cur) {
                        atomicAdd(&P.gsum[cur * H + 2 * lane], acc0);
                        atomicAdd(&P.gsum[cur * H + 2 * lane + 1], acc1);
                        acc0 = 0.f;
                        acc1 = 0.f;
                        cur = g;
                    }
                    unsigned int w = Bu[(size_t)(base + j) * 64 + lane];
                    acc0 += BFLO(w);
                    acc1 += BFHI(w);
                    ++j;
                }
            }
            atomicAdd(&P.gsum[cur * H + 2 * lane], acc0);
            atomicAdd(&P.gsum[cur * H + 2 * lane + 1], acc1);
        }
    }
    grid.sync();

    // ---- P10: head (blocks 0..63) ----
    if (bid < NGRAPH) {
        float* gv = (float*)smraw;
        float* hid = gv + H;
        float* lg = hid + H;
        int gr = bid, f = t;
        int cntg = P.gstart[gr + 1] - P.gstart[gr];
        if (f < H) gv[f] = P.gsum[gr * H + f] / fmaxf((float)cntg, 1.f);
        __syncthreads();
        if (f < H) {
            float acc = P.fb1[f];
            for (int k = 0; k < H; ++k) acc = fmaf(gv[k], P.fW1[k * H + f], acc);
            hid[f] = fmaxf(acc, 0.f);
        }
        __syncthreads();
        if (f < DOUT) {
            float a = P.fb2[f];
            for (int k = 0; k < H; ++k) a = fmaf(hid[k], P.fW2[k * DOUT + f], a);
            lg[f] = a;
        }
        __syncthreads();
        if (f < DOUT) {
            float mx = -1e30f;
            for (int j = 0; j < DOUT; ++j) mx = fmaxf(mx, lg[j]);
            float ssum = 0.f;
            for (int j = 0; j < DOUT; ++j) ssum += expf(lg[j] - mx);
            P.out[gr * DOUT + f] = expf(lg[f] - mx) / ssum;
        }
    }
}

// ---------------- launch ----------------

extern "C" void kernel_launch(void* const* d_in, const int* in_sizes, int n_in,
                              void* d_out, int out_size, void* d_ws, size_t ws_size,
                              hipStream_t stream) {
    int N = in_sizes[0] / H;
    int E = in_sizes[1] / 2;

    char* ws = (char*)d_ws;
    size_t off = 0;
    auto alloc = [&](size_t bytes) {
        void* p = ws + off;
        off = (off + bytes + 255) & ~(size_t)255;
        return p;
    };
    int* row_ptr = (int*)alloc((size_t)(N + 1) * 4);
    int* col = (int*)alloc((size_t)E * 4);
    float* dinv = (float*)alloc((size_t)N * 4);
    int* gstart = (int*)alloc(512);
    int* bcnt = (int*)alloc(NBUCK_MAX * 4);
    int* bstart = (int*)alloc((NBUCK_MAX + 1) * 4);
    int* bfill = (int*)alloc(NBUCK_MAX * 4);
    unsigned int* Wbf1 = (unsigned int*)alloc(128 * 64 * 4);
    unsigned int* Wbf2 = (unsigned int*)alloc(128 * 64 * 4);
    float* gsum = (float*)alloc((size_t)NGRAPH * H * 4);
    unsigned char* Af8 = (unsigned char*)alloc((size_t)N * H * 4);
    unsigned int* Bp = (unsigned int*)alloc((size_t)N * H * 4);
    (void)ws_size;

    int bshift = 0;
    while (((N - 1) >> bshift) >= NBUCK_MAX) ++bshift;
    int nbuck = ((N - 1) >> bshift) + 1;
    int nst = (E + SORT_TILE - 1) / SORT_TILE;

    MegaParams mp;
    mp.x = (const float*)d_in[0];
    mp.srcI = (const int*)d_in[1];
    mp.dstI = (const int*)d_in[1] + E;
    mp.batch = (const int*)d_in[2];
    mp.W1 = (const float*)d_in[3];
    mp.b1 = (const float*)d_in[4];
    mp.W2 = (const float*)d_in[5];
    mp.b2 = (const float*)d_in[6];
    mp.fW1 = (const float*)d_in[7];
    mp.fb1 = (const float*)d_in[8];
    mp.fW2 = (const float*)d_in[9];
    mp.fb2 = (const float*)d_in[10];
    mp.out = (float*)d_out;
    mp.row_ptr = row_ptr;
    mp.col = col;
    mp.dinv = dinv;
    mp.gstart = gstart;
    mp.bcnt = bcnt;
    mp.bstart = bstart;
    mp.bfill = bfill;
    mp.Wbf1 = Wbf1;
    mp.Wbf2 = Wbf2;
    mp.gsum = gsum;
    mp.Af8 = Af8;
    mp.Bp = Bp;
    mp.N = N;
    mp.E = E;
    mp.bshift = bshift;
    mp.nbuck = nbuck;
    mp.nst = nst;

    int maxb = 0;
    hipOccupancyMaxActiveBlocksPerMultiprocessor(&maxb, (const void*)mega_kernel, 256, 0);
    if (maxb < 1) maxb = 1;
    int dev = 0;
    hipGetDevice(&dev);
    hipDeviceProp_t prop;
    hipGetDeviceProperties(&prop, dev);
    int ncu = prop.multiProcessorCount;
    if (ncu < 1) ncu = 256;
    long long cap = (long long)maxb * ncu;
    int G = (cap > 2048) ? 2048 : (int)cap;
    if (G < 66) G = 66;  // need W-prep role blocks; MI355X capacity >= 256 regardless

    void* args[] = {&mp};
    hipLaunchCooperativeKernel((const void*)mega_kernel, dim3(G), dim3(256), args, 0, stream);
}

// Round 21
// 203.988 us; speedup vs baseline: 4.6161x; 4.6133x over previous
//
#include <hip/hip_runtime.h>
#include <hip/hip_bf16.h>

#define H 128
#define DOUT 32
#define NGRAPH 64
#define PCHUNK 64
#define SORT_TILE 4096
#define NBUCK_MAX 128
#define BNODES 1024  // nodes per bucket (bshift=10 for N=100000)

typedef __attribute__((ext_vector_type(8))) short bf16x8;
typedef __attribute__((ext_vector_type(4))) float f32x4;
typedef __attribute__((ext_vector_type(2))) float f32x2;
union U4B {
    uint4 u;
    bf16x8 b;
};

// bf16 helpers (RTN-even pack, bit-shift unpack)
static __device__ __forceinline__ unsigned short f2bf(float v) {
    unsigned int u = __float_as_uint(v);
    unsigned int r = (u + 0x7FFFu + ((u >> 16) & 1u)) >> 16;
    return (unsigned short)r;
}
#define BFLO(w) __uint_as_float((w) << 16)
#define BFHI(w) __uint_as_float((w) & 0xFFFF0000u)

// ---------------- setup: gsum zero + prep_w + batch_bounds + bucket hist -------
__global__ __launch_bounds__(256) void setup_kernel(
    const int* __restrict__ batch, int N, int* __restrict__ gstart,
    const float* __restrict__ W1, const float* __restrict__ W2,
    unsigned int* __restrict__ Wbf1, unsigned int* __restrict__ Wbf2,
    float* __restrict__ gsum, const int* __restrict__ dst, int E, int bshift, int nbuck,
    int nbb, int nst, int* __restrict__ bcnt, int* __restrict__ tick,
    int* __restrict__ bstart, int* __restrict__ bfill) {
    int b = blockIdx.x, t = threadIdx.x;
    if (b == 0) {
        for (int j = t; j < NGRAPH * H; j += 256) gsum[j] = 0.f;
        return;
    }
    if (b <= 64) {
        int pb = b - 1;
        const float* W = (pb < 32) ? W1 : W2;
        unsigned int* Wbf = (pb < 32) ? Wbf1 : Wbf2;
        int q = (pb & 31) * 256 + t;  // 0..8191
        int colq = q >> 6, j = q & 63;
        int p = j >> 2, wI = j & 3;
        int cq = p ^ (colq & 15);
        int k0 = 8 * cq + 2 * wI;
        Wbf[q] = (unsigned int)f2bf(W[k0 * H + colq]) |
                 ((unsigned int)f2bf(W[(k0 + 1) * H + colq]) << 16);
        return;
    }
    if (b <= 64 + nbb) {
        int i = (b - 65) * 256 + t;
        if (i < N) {
            int bb = batch[i];
            int bp = (i == 0) ? -1 : batch[i - 1];
            for (int g = bp + 1; g <= bb; ++g) gstart[g] = i;
            if (i == N - 1)
                for (int g = bb + 1; g <= NGRAPH; ++g) gstart[g] = N;
        }
        return;
    }
    // ---- histogram tile ----
    __shared__ int lh[NBUCK_MAX];
    __shared__ int done;
    __shared__ int scnt[NBUCK_MAX];
    int tile = b - 65 - nbb;
    if (t < NBUCK_MAX) lh[t] = 0;
    __syncthreads();
    int base = tile * SORT_TILE;
    int cnt = E - base;
    if (cnt > SORT_TILE) cnt = SORT_TILE;
    for (int j = t; j < cnt; j += 256) atomicAdd(&lh[dst[base + j] >> bshift], 1);
    __syncthreads();
    if (t < NBUCK_MAX && lh[t]) atomicAdd(&bcnt[t], lh[t]);
    __syncthreads();
    if (t == 0) {
        __threadfence();
        done = (atomicAdd(tick, 1) == nst - 1) ? 1 : 0;
    }
    __syncthreads();
    if (done) {
        if (t < nbuck) scnt[t] = atomicAdd(&bcnt[t], 0);  // coherent read
        __syncthreads();
        if (t == 0) {
            int run = 0;
            for (int k = 0; k < nbuck; ++k) {
                bstart[k] = run;
                bfill[k] = run;
                run += scnt[k];
            }
            bstart[nbuck] = run;  // == E
        }
    }
}

// ---------------- scatter: direct write, 1.5KB LDS, full occupancy ------------
__global__ __launch_bounds__(256) void bucket_scatter_kernel(const int* __restrict__ src,
                                                             const int* __restrict__ dst, int E,
                                                             int bshift, int* __restrict__ bfill,
                                                             unsigned int* __restrict__ es) {
    __shared__ int lh[NBUCK_MAX], lfill[NBUCK_MAX], gbase[NBUCK_MAX];
    int t = threadIdx.x;
    unsigned int mask = (1u << bshift) - 1u;
    if (t < NBUCK_MAX) {
        lh[t] = 0;
        lfill[t] = 0;
    }
    __syncthreads();
    int base = blockIdx.x * SORT_TILE;
    int cnt = E - base;
    if (cnt > SORT_TILE) cnt = SORT_TILE;
    for (int j = t; j < cnt; j += 256) atomicAdd(&lh[dst[base + j] >> bshift], 1);
    __syncthreads();
    if (t < NBUCK_MAX && lh[t] > 0) gbase[t] = atomicAdd(&bfill[t], lh[t]);
    __syncthreads();
    for (int j = t; j < cnt; j += 256) {
        int d = dst[base + j];
        int b = d >> bshift;
        int r = atomicAdd(&lfill[b], 1);
        es[gbase[b] + r] = ((unsigned int)src[base + j] << bshift) | ((unsigned int)d & mask);
    }
}

// ---------------- per-bucket counting sort: emits col, row_ptr, dinv ----------
__global__ __launch_bounds__(1024) void bucket_sort2_kernel(const unsigned int* __restrict__ es,
                                                            const int* __restrict__ bstart,
                                                            int bshift, int nbuck, int N, int E,
                                                            int* __restrict__ col,
                                                            int* __restrict__ row_ptr,
                                                            float* __restrict__ dinv) {
    __shared__ int cnt[BNODES];
    __shared__ int sc[BNODES];
    int b = blockIdx.x, t = threadIdx.x;
    unsigned int mask = (1u << bshift) - 1u;
    int nodebase = b << bshift;
    int nodes_here = N - nodebase;
    if (nodes_here > BNODES) nodes_here = BNODES;
    int s = bstart[b], e = bstart[b + 1];
    cnt[t] = 0;
    __syncthreads();
    for (int j = s + t; j < e; j += 1024) atomicAdd(&cnt[es[j] & mask], 1);
    __syncthreads();
    sc[t] = cnt[t];
    __syncthreads();
    for (int off = 1; off < BNODES; off <<= 1) {
        int x = (t >= off) ? sc[t - off] : 0;
        __syncthreads();
        sc[t] += x;
        __syncthreads();
    }
    int excl = sc[t] - cnt[t];
    __syncthreads();
    sc[t] = excl;
    if (t < nodes_here) {
        row_ptr[nodebase + t] = s + excl;
        dinv[nodebase + t] = rsqrtf(1.0f + (float)cnt[t]);
    }
    if (b == nbuck - 1 && t == 0) row_ptr[N] = E;
    __syncthreads();
    for (int j = s + t; j < e; j += 1024) {
        unsigned int p = es[j];
        int local = p & mask;
        int pos = s + atomicAdd(&sc[local], 1);
        col[pos] = (int)(p >> bshift);
    }
}

// ---------------- MFMA matmul (fp8 e4m3 output: the gathered operand) ---------
template <int IN_BF16>
__global__ __launch_bounds__(256) void mm_mfma_kernel(const void* __restrict__ Xv,
                                                      const unsigned int* __restrict__ Wbf,
                                                      const float* __restrict__ dinv,
                                                      unsigned char* __restrict__ Out, int M) {
    __shared__ unsigned int wlds[128 * 64];
    int t = threadIdx.x;
    const uint4* Wv = (const uint4*)Wbf;
#pragma unroll
    for (int it = 0; it < 8; ++it)
        ((uint4*)wlds)[t + it * 256] = Wv[t + it * 256];
    __syncthreads();

    int wv = t >> 6, l = t & 63;
    int l16 = l & 15, lk = l >> 4;
    int rowbase = blockIdx.x * 128 + wv * 32;

    f32x4 acc[2][8];
#pragma unroll
    for (int rt = 0; rt < 2; ++rt)
#pragma unroll
        for (int nt = 0; nt < 8; ++nt) acc[rt][nt] = (f32x4){0.f, 0.f, 0.f, 0.f};

#pragma unroll
    for (int ks = 0; ks < 4; ++ks) {
        U4B afr[2];
#pragma unroll
        for (int rt = 0; rt < 2; ++rt) {
            int row = rowbase + rt * 16 + l16;
            if (IN_BF16) {
                uint4 v = make_uint4(0u, 0u, 0u, 0u);
                if (row < M) v = *((const uint4*)Xv + (size_t)row * 16 + 4 * ks + lk);
                afr[rt].u = v;
            } else {
                const float* X = (const float*)Xv;
                float4 v0 = make_float4(0.f, 0.f, 0.f, 0.f), v1 = v0;
                if (row < M) {
                    v0 = *reinterpret_cast<const float4*>(X + (size_t)row * H + 32 * ks +
                                                          8 * lk);
                    v1 = *reinterpret_cast<const float4*>(X + (size_t)row * H + 32 * ks +
                                                          8 * lk + 4);
                }
                afr[rt].u.x = (unsigned int)f2bf(v0.x) | ((unsigned int)f2bf(v0.y) << 16);
                afr[rt].u.y = (unsigned int)f2bf(v0.z) | ((unsigned int)f2bf(v0.w) << 16);
                afr[rt].u.z = (unsigned int)f2bf(v1.x) | ((unsigned int)f2bf(v1.y) << 16);
                afr[rt].u.w = (unsigned int)f2bf(v1.z) | ((unsigned int)f2bf(v1.w) << 16);
            }
        }
#pragma unroll
        for (int nt = 0; nt < 8; ++nt) {
            int colB = nt * 16 + l16;
            int c = 4 * ks + lk;
            int p = c ^ (colB & 15);
            U4B bfr;
            bfr.u = *reinterpret_cast<const uint4*>(&wlds[colB * 64 + p * 4]);
            acc[0][nt] = __builtin_amdgcn_mfma_f32_16x16x32_bf16(afr[0].b, bfr.b, acc[0][nt],
                                                                 0, 0, 0);
            acc[1][nt] = __builtin_amdgcn_mfma_f32_16x16x32_bf16(afr[1].b, bfr.b, acc[1][nt],
                                                                 0, 0, 0);
        }
    }

#pragma unroll
    for (int rt = 0; rt < 2; ++rt) {
#pragma unroll
        for (int r = 0; r < 4; ++r) {
            int row = rowbase + rt * 16 + lk * 4 + r;
            if (row < M) {
                float dsc = dinv[row];
                unsigned char* Orow = Out + (size_t)row * H;
#pragma unroll
                for (int nt = 0; nt < 8; ++nt) {
                    int pk8 = __builtin_amdgcn_cvt_pk_fp8_f32(acc[rt][nt][r] * dsc, 0.f, 0, 0);
                    Orow[nt * 16 + l16] = (unsigned char)(pk8 & 0xFF);
                }
            }
        }
    }
}

// ---------------- aggregation: fp8 gathers, 16-deep, 2 rows/wave --------------
__global__ __launch_bounds__(256) void agg_fp8_kernel(
    const unsigned int* __restrict__ Au, const int* __restrict__ row_ptr,
    const int* __restrict__ col, const float* __restrict__ dinv,
    const float* __restrict__ bias, unsigned int* __restrict__ OutBf, int N) {
    int wave = threadIdx.x >> 6;
    int lane = threadIdx.x & 63;
    int half = lane >> 5, fl = lane & 31;
    int i = blockIdx.x * 8 + wave * 2 + half;
    if (i >= N) return;
    int s = row_ptr[i], e = row_ptr[i + 1];
    unsigned int ws = Au[(size_t)i * 32 + fl];  // self-loop term (4 fp8)
    f32x2 slo = __builtin_amdgcn_cvt_pk_f32_fp8((int)ws, false);
    f32x2 shi = __builtin_amdgcn_cvt_pk_f32_fp8((int)ws, true);
    float a0 = slo[0], a1 = slo[1], a2 = shi[0], a3 = shi[1];
    int j = s;
    for (; j + 16 <= e; j += 16) {
        unsigned int w[16];
#pragma unroll
        for (int q = 0; q < 16; ++q) w[q] = Au[(size_t)col[j + q] * 32 + fl];
#pragma unroll
        for (int q = 0; q < 16; ++q) {
            f32x2 lo = __builtin_amdgcn_cvt_pk_f32_fp8((int)w[q], false);
            f32x2 hi = __builtin_amdgcn_cvt_pk_f32_fp8((int)w[q], true);
            a0 += lo[0];
            a1 += lo[1];
            a2 += hi[0];
            a3 += hi[1];
        }
    }
    for (; j + 4 <= e; j += 4) {
        unsigned int w[4];
#pragma unroll
        for (int q = 0; q < 4; ++q) w[q] = Au[(size_t)col[j + q] * 32 + fl];
#pragma unroll
        for (int q = 0; q < 4; ++q) {
            f32x2 lo = __builtin_amdgcn_cvt_pk_f32_fp8((int)w[q], false);
            f32x2 hi = __builtin_amdgcn_cvt_pk_f32_fp8((int)w[q], true);
            a0 += lo[0];
            a1 += lo[1];
            a2 += hi[0];
            a3 += hi[1];
        }
    }
    for (; j < e; ++j) {
        unsigned int w = Au[(size_t)col[j] * 32 + fl];
        f32x2 lo = __builtin_amdgcn_cvt_pk_f32_fp8((int)w, false);
        f32x2 hi = __builtin_amdgcn_cvt_pk_f32_fp8((int)w, true);
        a0 += lo[0];
        a1 += lo[1];
        a2 += hi[0];
        a3 += hi[1];
    }
    float d = dinv[i];
    float4 bs = *reinterpret_cast<const float4*>(bias + 4 * fl);
    float o0 = fmaxf(fmaf(d, a0, bs.x), 0.f);
    float o1 = fmaxf(fmaf(d, a1, bs.y), 0.f);
    float o2 = fmaxf(fmaf(d, a2, bs.z), 0.f);
    float o3 = fmaxf(fmaf(d, a3, bs.w), 0.f);
    uint2 o;
    o.x = (unsigned int)f2bf(o0) | ((unsigned int)f2bf(o1) << 16);
    o.y = (unsigned int)f2bf(o2) | ((unsigned int)f2bf(o3) << 16);
    ((uint2*)OutBf)[(size_t)i * 32 + fl] = o;
}

// ---------------- pooling (4 waves/block, 4-row unrolled fast path) ------------

__global__ __launch_bounds__(256) void pool_partial(const unsigned int* __restrict__ Bu,
                                                    const int* __restrict__ batch,
                                                    float* __restrict__ gsum, int N) {
    __shared__ int sb[4][PCHUNK];
    int wave = threadIdx.x >> 6, lane = threadIdx.x & 63;
    int base = (blockIdx.x * 4 + wave) * PCHUNK;
    int n_here = N - base;
    if (n_here > PCHUNK) n_here = PCHUNK;
    if (n_here > 0)
        for (int j = lane; j < n_here; j += 64) sb[wave][j] = batch[base + j];
    __syncthreads();
    if (n_here <= 0) return;
    float acc0 = 0.f, acc1 = 0.f;
    int cur = sb[wave][0];
    int j = 0;
    while (j < n_here) {
        if (j + 4 <= n_here && sb[wave][j] == cur && sb[wave][j + 1] == cur &&
            sb[wave][j + 2] == cur && sb[wave][j + 3] == cur) {
            unsigned int w0 = Bu[(size_t)(base + j) * 64 + lane];
            unsigned int w1 = Bu[(size_t)(base + j + 1) * 64 + lane];
            unsigned int w2 = Bu[(size_t)(base + j + 2) * 64 + lane];
            unsigned int w3 = Bu[(size_t)(base + j + 3) * 64 + lane];
            acc0 += BFLO(w0) + BFLO(w1);
            acc1 += BFHI(w0) + BFHI(w1);
            acc0 += BFLO(w2) + BFLO(w3);
            acc1 += BFHI(w2) + BFHI(w3);
            j += 4;
        } else {
            int g = sb[wave][j];
            if (g != cur) {
                atomicAdd(&gsum[cur * H + 2 * lane], acc0);
                atomicAdd(&gsum[cur * H + 2 * lane + 1], acc1);
                acc0 = 0.f;
                acc1 = 0.f;
                cur = g;
            }
            unsigned int w = Bu[(size_t)(base + j) * 64 + lane];
            acc0 += BFLO(w);
            acc1 += BFHI(w);
            ++j;
        }
    }
    atomicAdd(&gsum[cur * H + 2 * lane], acc0);
    atomicAdd(&gsum[cur * H + 2 * lane + 1], acc1);
}

// head + pool_final fused: gv = gsum/cnt
__global__ __launch_bounds__(128) void head_kernel(const float* __restrict__ gsum,
                                                   const int* __restrict__ gstart,
                                                   const float* __restrict__ fW1,
                                                   const float* __restrict__ fb1,
                                                   const float* __restrict__ fW2,
                                                   const float* __restrict__ fb2,
                                                   float* __restrict__ out) {
    __shared__ float gv[H], hid[H], lg[DOUT];
    int gr = blockIdx.x, f = threadIdx.x;
    int cnt = gstart[gr + 1] - gstart[gr];
    gv[f] = gsum[gr * H + f] / fmaxf((float)cnt, 1.f);
    __syncthreads();
    float acc = fb1[f];
    for (int k = 0; k < H; ++k) acc = fmaf(gv[k], fW1[k * H + f], acc);
    hid[f] = fmaxf(acc, 0.f);
    __syncthreads();
    if (f < DOUT) {
        float a = fb2[f];
        for (int k = 0; k < H; ++k) a = fmaf(hid[k], fW2[k * DOUT + f], a);
        lg[f] = a;
    }
    __syncthreads();
    if (f < DOUT) {
        float mx = -1e30f;
        for (int j = 0; j < DOUT; ++j) mx = fmaxf(mx, lg[j]);
        float ssum = 0.f;
        for (int j = 0; j < DOUT; ++j) ssum += expf(lg[j] - mx);
        out[gr * DOUT + f] = expf(lg[f] - mx) / ssum;
    }
}

// ---------------- launch ----------------

extern "C" void kernel_launch(void* const* d_in, const int* in_sizes, int n_in,
                              void* d_out, int out_size, void* d_ws, size_t ws_size,
                              hipStream_t stream) {
    const float* x = (const float*)d_in[0];
    const int* edge = (const int*)d_in[1];
    const int* batch = (const int*)d_in[2];
    const float* W1 = (const float*)d_in[3];
    const float* b1 = (const float*)d_in[4];
    const float* W2 = (const float*)d_in[5];
    const float* b2 = (const float*)d_in[6];
    const float* fW1 = (const float*)d_in[7];
    const float* fb1 = (const float*)d_in[8];
    const float* fW2 = (const float*)d_in[9];
    const float* fb2 = (const float*)d_in[10];
    float* out = (float*)d_out;

    int N = in_sizes[0] / H;
    int E = in_sizes[1] / 2;
    const int* srcI = edge;
    const int* dstI = edge + E;

    char* ws = (char*)d_ws;
    size_t off = 0;
    auto alloc = [&](size_t bytes) {
        void* p = ws + off;
        off = (off + bytes + 255) & ~(size_t)255;
        return p;
    };
    int* row_ptr = (int*)alloc((size_t)(N + 1) * 4);
    int* col = (int*)alloc((size_t)E * 4);
    float* dinv = (float*)alloc((size_t)N * 4);
    int* gstart = (int*)alloc(512);
    int* bctk = (int*)alloc(192 * 4);  // bcnt[128] + tick (zeroed together)
    int* bstart = (int*)alloc((NBUCK_MAX + 1) * 4);
    int* bfill = (int*)alloc(NBUCK_MAX * 4);
    unsigned int* Wbf1 = (unsigned int*)alloc(128 * 64 * 4);
    unsigned int* Wbf2 = (unsigned int*)alloc(128 * 64 * 4);
    float* gsum = (float*)alloc((size_t)NGRAPH * H * 4);
    // A region: holds es (E*4B packed) during CSR build, then fp8 activations
    unsigned char* Af8 = (unsigned char*)alloc((size_t)N * H * 4);
    unsigned int* Bbf = (unsigned int*)alloc((size_t)N * H * 4);
    (void)ws_size;

    int* bcnt = bctk;
    int* tick = bctk + 128;
    unsigned int* es = (unsigned int*)Af8;  // consumed by sort2 before mm1 writes

    int bshift = 0;
    while (((N - 1) >> bshift) >= NBUCK_MAX) ++bshift;
    int nbuck = ((N - 1) >> bshift) + 1;

    int nst = (E + SORT_TILE - 1) / SORT_TILE;
    int nbb = (N + 255) / 256;

    hipMemsetAsync(bctk, 0, 192 * 4, stream);
    setup_kernel<<<65 + nbb + nst, 256, 0, stream>>>(batch, N, gstart, W1, W2, Wbf1, Wbf2,
                                                     gsum, dstI, E, bshift, nbuck, nbb, nst,
                                                     bcnt, tick, bstart, bfill);
    bucket_scatter_kernel<<<nst, 256, 0, stream>>>(srcI, dstI, E, bshift, bfill, es);
    bucket_sort2_kernel<<<nbuck, 1024, 0, stream>>>(es, bstart, bshift, nbuck, N, E, col,
                                                    row_ptr, dinv);

    int mmblocks = (N + 127) / 128;
    int aggblocks = (N + 7) / 8;
    mm_mfma_kernel<0><<<mmblocks, 256, 0, stream>>>(x, Wbf1, dinv, Af8, N);
    agg_fp8_kernel<<<aggblocks, 256, 0, stream>>>((const unsigned int*)Af8, row_ptr, col,
                                                  dinv, b1, Bbf, N);
    mm_mfma_kernel<1><<<mmblocks, 256, 0, stream>>>(Bbf, Wbf2, dinv, Af8, N);
    agg_fp8_kernel<<<aggblocks, 256, 0, stream>>>((const unsigned int*)Af8, row_ptr, col,
                                                  dinv, b2, Bbf, N);
    pool_partial<<<(N + 4 * PCHUNK - 1) / (4 * PCHUNK), 256, 0, stream>>>(Bbf, batch, gsum, N);
    head_kernel<<<NGRAPH, 128, 0, stream>>>(gsum, gstart, fW1, fb1, fW2, fb2, out);
}

// Round 22
// 203.718 us; speedup vs baseline: 4.6222x; 1.0013x over previous
//
#include <hip/hip_runtime.h>
#include <hip/hip_bf16.h>

#define H 128
#define DOUT 32
#define NGRAPH 64
#define PCHUNK 64
#define SORT_TILE 4096
#define NBUCK_MAX 128
#define BNODES 1024  // nodes per bucket (bshift=10 for N=100000)

typedef __attribute__((ext_vector_type(8))) short bf16x8;
typedef __attribute__((ext_vector_type(4))) float f32x4;
typedef __attribute__((ext_vector_type(2))) float f32x2;
union U4B {
    uint4 u;
    bf16x8 b;
};

// bf16 helpers (RTN-even pack, bit-shift unpack)
static __device__ __forceinline__ unsigned short f2bf(float v) {
    unsigned int u = __float_as_uint(v);
    unsigned int r = (u + 0x7FFFu + ((u >> 16) & 1u)) >> 16;
    return (unsigned short)r;
}
#define BFLO(w) __uint_as_float((w) << 16)
#define BFHI(w) __uint_as_float((w) & 0xFFFF0000u)

// ---------------- setup: gsum zero + prep_w + batch_bounds + bucket hist -------
__global__ __launch_bounds__(256) void setup_kernel(
    const int* __restrict__ batch, int N, int* __restrict__ gstart,
    const float* __restrict__ W1, const float* __restrict__ W2,
    unsigned int* __restrict__ Wbf1, unsigned int* __restrict__ Wbf2,
    float* __restrict__ gsum, const int* __restrict__ dst, int E, int bshift, int nbuck,
    int nbb, int nst, int* __restrict__ bcnt, int* __restrict__ tick,
    int* __restrict__ bstart, int* __restrict__ bfill) {
    int b = blockIdx.x, t = threadIdx.x;
    if (b == 0) {
        for (int j = t; j < NGRAPH * H; j += 256) gsum[j] = 0.f;
        return;
    }
    if (b <= 64) {
        int pb = b - 1;
        const float* W = (pb < 32) ? W1 : W2;
        unsigned int* Wbf = (pb < 32) ? Wbf1 : Wbf2;
        int q = (pb & 31) * 256 + t;  // 0..8191
        int colq = q >> 6, j = q & 63;
        int p = j >> 2, wI = j & 3;
        int cq = p ^ (colq & 15);
        int k0 = 8 * cq + 2 * wI;
        Wbf[q] = (unsigned int)f2bf(W[k0 * H + colq]) |
                 ((unsigned int)f2bf(W[(k0 + 1) * H + colq]) << 16);
        return;
    }
    if (b <= 64 + nbb) {
        int i = (b - 65) * 256 + t;
        if (i < N) {
            int bb = batch[i];
            int bp = (i == 0) ? -1 : batch[i - 1];
            for (int g = bp + 1; g <= bb; ++g) gstart[g] = i;
            if (i == N - 1)
                for (int g = bb + 1; g <= NGRAPH; ++g) gstart[g] = N;
        }
        return;
    }
    // ---- histogram tile ----
    __shared__ int lh[NBUCK_MAX];
    __shared__ int done;
    __shared__ int scnt[NBUCK_MAX];
    int tile = b - 65 - nbb;
    if (t < NBUCK_MAX) lh[t] = 0;
    __syncthreads();
    int base = tile * SORT_TILE;
    int cnt = E - base;
    if (cnt > SORT_TILE) cnt = SORT_TILE;
    for (int j = t; j < cnt; j += 256) atomicAdd(&lh[dst[base + j] >> bshift], 1);
    __syncthreads();
    if (t < NBUCK_MAX && lh[t]) atomicAdd(&bcnt[t], lh[t]);
    __syncthreads();
    if (t == 0) {
        __threadfence();
        done = (atomicAdd(tick, 1) == nst - 1) ? 1 : 0;
    }
    __syncthreads();
    if (done) {
        if (t < nbuck) scnt[t] = atomicAdd(&bcnt[t], 0);  // coherent read
        __syncthreads();
        if (t == 0) {
            int run = 0;
            for (int k = 0; k < nbuck; ++k) {
                bstart[k] = run;
                bfill[k] = run;
                run += scnt[k];
            }
            bstart[nbuck] = run;  // == E
        }
    }
}

// ---------------- scatter: direct write, 1.5KB LDS, full occupancy ------------
__global__ __launch_bounds__(256) void bucket_scatter_kernel(const int* __restrict__ src,
                                                             const int* __restrict__ dst, int E,
                                                             int bshift, int* __restrict__ bfill,
                                                             unsigned int* __restrict__ es) {
    __shared__ int lh[NBUCK_MAX], lfill[NBUCK_MAX], gbase[NBUCK_MAX];
    int t = threadIdx.x;
    unsigned int mask = (1u << bshift) - 1u;
    if (t < NBUCK_MAX) {
        lh[t] = 0;
        lfill[t] = 0;
    }
    __syncthreads();
    int base = blockIdx.x * SORT_TILE;
    int cnt = E - base;
    if (cnt > SORT_TILE) cnt = SORT_TILE;
    for (int j = t; j < cnt; j += 256) atomicAdd(&lh[dst[base + j] >> bshift], 1);
    __syncthreads();
    if (t < NBUCK_MAX && lh[t] > 0) gbase[t] = atomicAdd(&bfill[t], lh[t]);
    __syncthreads();
    for (int j = t; j < cnt; j += 256) {
        int d = dst[base + j];
        int b = d >> bshift;
        int r = atomicAdd(&lfill[b], 1);
        es[gbase[b] + r] = ((unsigned int)src[base + j] << bshift) | ((unsigned int)d & mask);
    }
}

// ---------------- per-bucket counting sort: emits col, row_ptr, dinv ----------
__global__ __launch_bounds__(1024) void bucket_sort2_kernel(const unsigned int* __restrict__ es,
                                                            const int* __restrict__ bstart,
                                                            int bshift, int nbuck, int N, int E,
                                                            int* __restrict__ col,
                                                            int* __restrict__ row_ptr,
                                                            float* __restrict__ dinv) {
    __shared__ int cnt[BNODES];
    __shared__ int sc[BNODES];
    int b = blockIdx.x, t = threadIdx.x;
    unsigned int mask = (1u << bshift) - 1u;
    int nodebase = b << bshift;
    int nodes_here = N - nodebase;
    if (nodes_here > BNODES) nodes_here = BNODES;
    int s = bstart[b], e = bstart[b + 1];
    cnt[t] = 0;
    __syncthreads();
    for (int j = s + t; j < e; j += 1024) atomicAdd(&cnt[es[j] & mask], 1);
    __syncthreads();
    sc[t] = cnt[t];
    __syncthreads();
    for (int off = 1; off < BNODES; off <<= 1) {
        int x = (t >= off) ? sc[t - off] : 0;
        __syncthreads();
        sc[t] += x;
        __syncthreads();
    }
    int excl = sc[t] - cnt[t];
    __syncthreads();
    sc[t] = excl;
    if (t < nodes_here) {
        row_ptr[nodebase + t] = s + excl;
        dinv[nodebase + t] = rsqrtf(1.0f + (float)cnt[t]);
    }
    if (b == nbuck - 1 && t == 0) row_ptr[N] = E;
    __syncthreads();
    for (int j = s + t; j < e; j += 1024) {
        unsigned int p = es[j];
        int local = p & mask;
        int pos = s + atomicAdd(&sc[local], 1);
        col[pos] = (int)(p >> bshift);
    }
}

// ---------------- MFMA matmul (fp8 e4m3 output: the gathered operand) ---------
template <int IN_BF16>
__global__ __launch_bounds__(256) void mm_mfma_kernel(const void* __restrict__ Xv,
                                                      const unsigned int* __restrict__ Wbf,
                                                      const float* __restrict__ dinv,
                                                      unsigned char* __restrict__ Out, int M) {
    __shared__ unsigned int wlds[128 * 64];
    int t = threadIdx.x;
    const uint4* Wv = (const uint4*)Wbf;
#pragma unroll
    for (int it = 0; it < 8; ++it)
        ((uint4*)wlds)[t + it * 256] = Wv[t + it * 256];
    __syncthreads();

    int wv = t >> 6, l = t & 63;
    int l16 = l & 15, lk = l >> 4;
    int rowbase = blockIdx.x * 128 + wv * 32;

    f32x4 acc[2][8];
#pragma unroll
    for (int rt = 0; rt < 2; ++rt)
#pragma unroll
        for (int nt = 0; nt < 8; ++nt) acc[rt][nt] = (f32x4){0.f, 0.f, 0.f, 0.f};

#pragma unroll
    for (int ks = 0; ks < 4; ++ks) {
        U4B afr[2];
#pragma unroll
        for (int rt = 0; rt < 2; ++rt) {
            int row = rowbase + rt * 16 + l16;
            if (IN_BF16) {
                uint4 v = make_uint4(0u, 0u, 0u, 0u);
                if (row < M) v = *((const uint4*)Xv + (size_t)row * 16 + 4 * ks + lk);
                afr[rt].u = v;
            } else {
                const float* X = (const float*)Xv;
                float4 v0 = make_float4(0.f, 0.f, 0.f, 0.f), v1 = v0;
                if (row < M) {
                    v0 = *reinterpret_cast<const float4*>(X + (size_t)row * H + 32 * ks +
                                                          8 * lk);
                    v1 = *reinterpret_cast<const float4*>(X + (size_t)row * H + 32 * ks +
                                                          8 * lk + 4);
                }
                afr[rt].u.x = (unsigned int)f2bf(v0.x) | ((unsigned int)f2bf(v0.y) << 16);
                afr[rt].u.y = (unsigned int)f2bf(v0.z) | ((unsigned int)f2bf(v0.w) << 16);
                afr[rt].u.z = (unsigned int)f2bf(v1.x) | ((unsigned int)f2bf(v1.y) << 16);
                afr[rt].u.w = (unsigned int)f2bf(v1.z) | ((unsigned int)f2bf(v1.w) << 16);
            }
        }
#pragma unroll
        for (int nt = 0; nt < 8; ++nt) {
            int colB = nt * 16 + l16;
            int c = 4 * ks + lk;
            int p = c ^ (colB & 15);
            U4B bfr;
            bfr.u = *reinterpret_cast<const uint4*>(&wlds[colB * 64 + p * 4]);
            acc[0][nt] = __builtin_amdgcn_mfma_f32_16x16x32_bf16(afr[0].b, bfr.b, acc[0][nt],
                                                                 0, 0, 0);
            acc[1][nt] = __builtin_amdgcn_mfma_f32_16x16x32_bf16(afr[1].b, bfr.b, acc[1][nt],
                                                                 0, 0, 0);
        }
    }

#pragma unroll
    for (int rt = 0; rt < 2; ++rt) {
#pragma unroll
        for (int r = 0; r < 4; ++r) {
            int row = rowbase + rt * 16 + lk * 4 + r;
            if (row < M) {
                float dsc = dinv[row];
                unsigned char* Orow = Out + (size_t)row * H;
#pragma unroll
                for (int nt = 0; nt < 8; ++nt) {
                    int pk8 = __builtin_amdgcn_cvt_pk_fp8_f32(acc[rt][nt][r] * dsc, 0.f, 0, 0);
                    Orow[nt * 16 + l16] = (unsigned char)(pk8 & 0xFF);
                }
            }
        }
    }
}

// ---------------- aggregation: fp8 gathers, 16-deep, 2 rows/wave --------------
__global__ __launch_bounds__(256) void agg_fp8_kernel(
    const unsigned int* __restrict__ Au, const int* __restrict__ row_ptr,
    const int* __restrict__ col, const float* __restrict__ dinv,
    const float* __restrict__ bias, unsigned int* __restrict__ OutBf, int N) {
    int wave = threadIdx.x >> 6;
    int lane = threadIdx.x & 63;
    int half = lane >> 5, fl = lane & 31;
    int i = blockIdx.x * 8 + wave * 2 + half;
    if (i >= N) return;
    int s = row_ptr[i], e = row_ptr[i + 1];
    unsigned int ws = Au[(size_t)i * 32 + fl];  // self-loop term (4 fp8)
    f32x2 slo = __builtin_amdgcn_cvt_pk_f32_fp8((int)ws, false);
    f32x2 shi = __builtin_amdgcn_cvt_pk_f32_fp8((int)ws, true);
    float a0 = slo[0], a1 = slo[1], a2 = shi[0], a3 = shi[1];
    int j = s;
    for (; j + 16 <= e; j += 16) {
        unsigned int w[16];
#pragma unroll
        for (int q = 0; q < 16; ++q) w[q] = Au[(size_t)col[j + q] * 32 + fl];
#pragma unroll
        for (int q = 0; q < 16; ++q) {
            f32x2 lo = __builtin_amdgcn_cvt_pk_f32_fp8((int)w[q], false);
            f32x2 hi = __builtin_amdgcn_cvt_pk_f32_fp8((int)w[q], true);
            a0 += lo[0];
            a1 += lo[1];
            a2 += hi[0];
            a3 += hi[1];
        }
    }
    for (; j + 4 <= e; j += 4) {
        unsigned int w[4];
#pragma unroll
        for (int q = 0; q < 4; ++q) w[q] = Au[(size_t)col[j + q] * 32 + fl];
#pragma unroll
        for (int q = 0; q < 4; ++q) {
            f32x2 lo = __builtin_amdgcn_cvt_pk_f32_fp8((int)w[q], false);
            f32x2 hi = __builtin_amdgcn_cvt_pk_f32_fp8((int)w[q], true);
            a0 += lo[0];
            a1 += lo[1];
            a2 += hi[0];
            a3 += hi[1];
        }
    }
    for (; j < e; ++j) {
        unsigned int w = Au[(size_t)col[j] * 32 + fl];
        f32x2 lo = __builtin_amdgcn_cvt_pk_f32_fp8((int)w, false);
        f32x2 hi = __builtin_amdgcn_cvt_pk_f32_fp8((int)w, true);
        a0 += lo[0];
        a1 += lo[1];
        a2 += hi[0];
        a3 += hi[1];
    }
    float d = dinv[i];
    float4 bs = *reinterpret_cast<const float4*>(bias + 4 * fl);
    float o0 = fmaxf(fmaf(d, a0, bs.x), 0.f);
    float o1 = fmaxf(fmaf(d, a1, bs.y), 0.f);
    float o2 = fmaxf(fmaf(d, a2, bs.z), 0.f);
    float o3 = fmaxf(fmaf(d, a3, bs.w), 0.f);
    uint2 o;
    o.x = (unsigned int)f2bf(o0) | ((unsigned int)f2bf(o1) << 16);
    o.y = (unsigned int)f2bf(o2) | ((unsigned int)f2bf(o3) << 16);
    ((uint2*)OutBf)[(size_t)i * 32 + fl] = o;
}

// ---------------- pooling (4 waves/block, 4-row unrolled fast path) ------------

__global__ __launch_bounds__(256) void pool_partial(const unsigned int* __restrict__ Bu,
                                                    const int* __restrict__ batch,
                                                    float* __restrict__ gsum, int N) {
    __shared__ int sb[4][PCHUNK];
    int wave = threadIdx.x >> 6, lane = threadIdx.x & 63;
    int base = (blockIdx.x * 4 + wave) * PCHUNK;
    int n_here = N - base;
    if (n_here > PCHUNK) n_here = PCHUNK;
    if (n_here > 0)
        for (int j = lane; j < n_here; j += 64) sb[wave][j] = batch[base + j];
    __syncthreads();
    if (n_here <= 0) return;
    float acc0 = 0.f, acc1 = 0.f;
    int cur = sb[wave][0];
    int j = 0;
    while (j < n_here) {
        if (j + 4 <= n_here && sb[wave][j] == cur && sb[wave][j + 1] == cur &&
            sb[wave][j + 2] == cur && sb[wave][j + 3] == cur) {
            unsigned int w0 = Bu[(size_t)(base + j) * 64 + lane];
            unsigned int w1 = Bu[(size_t)(base + j + 1) * 64 + lane];
            unsigned int w2 = Bu[(size_t)(base + j + 2) * 64 + lane];
            unsigned int w3 = Bu[(size_t)(base + j + 3) * 64 + lane];
            acc0 += BFLO(w0) + BFLO(w1);
            acc1 += BFHI(w0) + BFHI(w1);
            acc0 += BFLO(w2) + BFLO(w3);
            acc1 += BFHI(w2) + BFHI(w3);
            j += 4;
        } else {
            int g = sb[wave][j];
            if (g != cur) {
                atomicAdd(&gsum[cur * H + 2 * lane], acc0);
                atomicAdd(&gsum[cur * H + 2 * lane + 1], acc1);
                acc0 = 0.f;
                acc1 = 0.f;
                cur = g;
            }
            unsigned int w = Bu[(size_t)(base + j) * 64 + lane];
            acc0 += BFLO(w);
            acc1 += BFHI(w);
            ++j;
        }
    }
    atomicAdd(&gsum[cur * H + 2 * lane], acc0);
    atomicAdd(&gsum[cur * H + 2 * lane + 1], acc1);
}

// head + pool_final fused: gv = gsum/cnt
__global__ __launch_bounds__(128) void head_kernel(const float* __restrict__ gsum,
                                                   const int* __restrict__ gstart,
                                                   const float* __restrict__ fW1,
                                                   const float* __restrict__ fb1,
                                                   const float* __restrict__ fW2,
                                                   const float* __restrict__ fb2,
                                                   float* __restrict__ out) {
    __shared__ float gv[H], hid[H], lg[DOUT];
    int gr = blockIdx.x, f = threadIdx.x;
    int cnt = gstart[gr + 1] - gstart[gr];
    gv[f] = gsum[gr * H + f] / fmaxf((float)cnt, 1.f);
    __syncthreads();
    float acc = fb1[f];
    for (int k = 0; k < H; ++k) acc = fmaf(gv[k], fW1[k * H + f], acc);
    hid[f] = fmaxf(acc, 0.f);
    __syncthreads();
    if (f < DOUT) {
        float a = fb2[f];
        for (int k = 0; k < H; ++k) a = fmaf(hid[k], fW2[k * DOUT + f], a);
        lg[f] = a;
    }
    __syncthreads();
    if (f < DOUT) {
        float mx = -1e30f;
        for (int j = 0; j < DOUT; ++j) mx = fmaxf(mx, lg[j]);
        float ssum = 0.f;
        for (int j = 0; j < DOUT; ++j) ssum += expf(lg[j] - mx);
        out[gr * DOUT + f] = expf(lg[f] - mx) / ssum;
    }
}

// ---------------- launch ----------------

extern "C" void kernel_launch(void* const* d_in, const int* in_sizes, int n_in,
                              void* d_out, int out_size, void* d_ws, size_t ws_size,
                              hipStream_t stream) {
    const float* x = (const float*)d_in[0];
    const int* edge = (const int*)d_in[1];
    const int* batch = (const int*)d_in[2];
    const float* W1 = (const float*)d_in[3];
    const float* b1 = (const float*)d_in[4];
    const float* W2 = (const float*)d_in[5];
    const float* b2 = (const float*)d_in[6];
    const float* fW1 = (const float*)d_in[7];
    const float* fb1 = (const float*)d_in[8];
    const float* fW2 = (const float*)d_in[9];
    const float* fb2 = (const float*)d_in[10];
    float* out = (float*)d_out;

    int N = in_sizes[0] / H;
    int E = in_sizes[1] / 2;
    const int* srcI = edge;
    const int* dstI = edge + E;

    char* ws = (char*)d_ws;
    size_t off = 0;
    auto alloc = [&](size_t bytes) {
        void* p = ws + off;
        off = (off + bytes + 255) & ~(size_t)255;
        return p;
    };
    int* row_ptr = (int*)alloc((size_t)(N + 1) * 4);
    int* col = (int*)alloc((size_t)E * 4);
    float* dinv = (float*)alloc((size_t)N * 4);
    int* gstart = (int*)alloc(512);
    int* bctk = (int*)alloc(192 * 4);  // bcnt[128] + tick (zeroed together)
    int* bstart = (int*)alloc((NBUCK_MAX + 1) * 4);
    int* bfill = (int*)alloc(NBUCK_MAX * 4);
    unsigned int* Wbf1 = (unsigned int*)alloc(128 * 64 * 4);
    unsigned int* Wbf2 = (unsigned int*)alloc(128 * 64 * 4);
    float* gsum = (float*)alloc((size_t)NGRAPH * H * 4);
    // A region: holds es (E*4B packed) during CSR build, then fp8 activations
    unsigned char* Af8 = (unsigned char*)alloc((size_t)N * H * 4);
    unsigned int* Bbf = (unsigned int*)alloc((size_t)N * H * 4);
    (void)ws_size;

    int* bcnt = bctk;
    int* tick = bctk + 128;
    unsigned int* es = (unsigned int*)Af8;  // consumed by sort2 before mm1 writes

    int bshift = 0;
    while (((N - 1) >> bshift) >= NBUCK_MAX) ++bshift;
    int nbuck = ((N - 1) >> bshift) + 1;

    int nst = (E + SORT_TILE - 1) / SORT_TILE;
    int nbb = (N + 255) / 256;

    hipMemsetAsync(bctk, 0, 192 * 4, stream);
    setup_kernel<<<65 + nbb + nst, 256, 0, stream>>>(batch, N, gstart, W1, W2, Wbf1, Wbf2,
                                                     gsum, dstI, E, bshift, nbuck, nbb, nst,
                                                     bcnt, tick, bstart, bfill);
    bucket_scatter_kernel<<<nst, 256, 0, stream>>>(srcI, dstI, E, bshift, bfill, es);
    bucket_sort2_kernel<<<nbuck, 1024, 0, stream>>>(es, bstart, bshift, nbuck, N, E, col,
                                                    row_ptr, dinv);

    int mmblocks = (N + 127) / 128;
    int aggblocks = (N + 7) / 8;
    mm_mfma_kernel<0><<<mmblocks, 256, 0, stream>>>(x, Wbf1, dinv, Af8, N);
    agg_fp8_kernel<<<aggblocks, 256, 0, stream>>>((const unsigned int*)Af8, row_ptr, col,
                                                  dinv, b1, Bbf, N);
    mm_mfma_kernel<1><<<mmblocks, 256, 0, stream>>>(Bbf, Wbf2, dinv, Af8, N);
    agg_fp8_kernel<<<aggblocks, 256, 0, stream>>>((const unsigned int*)Af8, row_ptr, col,
                                                  dinv, b2, Bbf, N);
    pool_partial<<<(N + 4 * PCHUNK - 1) / (4 * PCHUNK), 256, 0, stream>>>(Bbf, batch, gsum, N);
    head_kernel<<<NGRAPH, 128, 0, stream>>>(gsum, gstart, fW1, fb1, fW2, fb2, out);
}